// Round 1
// 575.281 us; speedup vs baseline: 1.1572x; 1.1572x over previous
//
#include <hip/hip_runtime.h>
#include <math.h>
#include <stdint.h>

#define S_LEN 2048
#define D_DIM 4096
#define NHEAD 32
#define HDIM  128

typedef int      v4i __attribute__((ext_vector_type(4)));
typedef float    v4f __attribute__((ext_vector_type(4)));
typedef _Float16 v8h __attribute__((ext_vector_type(8)));

__device__ __forceinline__ float quant128(float x) {
  return fminf(fmaxf(rintf(x / 0.1f), -128.f), 127.f);
}
// async 16B global->LDS DMA; LDS side is wave-uniform base + lane*16
__device__ __forceinline__ void gl_lds16(const void* g, void* l) {
  __builtin_amdgcn_global_load_lds(
      (const __attribute__((address_space(1))) void*)g,
      (__attribute__((address_space(3))) void*)l, 16, 0, 0);
}

// ---------------- prep kernels ----------------
__global__ __launch_bounds__(256) void quant_hidden_k(const float* __restrict__ in,
                                                      int8_t* __restrict__ out) {
  const int idx = blockIdx.x * 256 + threadIdx.x;
  const float4 v = ((const float4*)in)[idx];
  const int q0 = (int)quant128(v.x), q1 = (int)quant128(v.y);
  const int q2 = (int)quant128(v.z), q3 = (int)quant128(v.w);
  ((int*)out)[idx] = (q0 & 0xff) | ((q1 & 0xff) << 8) | ((q2 & 0xff) << 16) | ((q3 & 0xff) << 24);
}

// fused f32->int8 convert of wq,wk,wv into one contiguous 48MB dst
__global__ __launch_bounds__(256) void wconv3_k(const float* __restrict__ a,
                                                const float* __restrict__ b,
                                                const float* __restrict__ c,
                                                int8_t* __restrict__ out) {
  const int which = blockIdx.x >> 14;
  const int sub = blockIdx.x & 16383;
  const float* src = (which == 0) ? a : (which == 1) ? b : c;
  const int idx = sub * 256 + threadIdx.x;
  const float4 v = ((const float4*)src)[idx];  // int4-valued floats, exact
  const int q0 = __float2int_rn(v.x), q1 = __float2int_rn(v.y);
  const int q2 = __float2int_rn(v.z), q3 = __float2int_rn(v.w);
  ((int*)out)[(size_t)which * 4194304 + idx] =
      (q0 & 0xff) | ((q1 & 0xff) << 8) | ((q2 & 0xff) << 16) | ((q3 & 0xff) << 24);
}

__global__ __launch_bounds__(256) void wconv_k(const float* __restrict__ in,
                                               int8_t* __restrict__ out) {
  const int idx = blockIdx.x * 256 + threadIdx.x;
  const float4 v = ((const float4*)in)[idx];
  const int q0 = __float2int_rn(v.x), q1 = __float2int_rn(v.y);
  const int q2 = __float2int_rn(v.z), q3 = __float2int_rn(v.w);
  ((int*)out)[idx] = (q0 & 0xff) | ((q1 & 0xff) << 8) | ((q2 & 0xff) << 16) | ((q3 & 0xff) << 24);
}

__global__ __launch_bounds__(256) void rope_tab_k(const int* __restrict__ pos,
                                                  float* __restrict__ ct,
                                                  float* __restrict__ st) {
  const int idx = blockIdx.x * 256 + threadIdx.x;  // [S][64]
  const int s = idx >> 6, j = idx & 63;
  const float inv = exp2f((float)j * -0.20762050593046016f);  // 10000^(-j/64)
  const float a = (float)pos[s] * inv;
  float si, c;
  sincosf(a, &si, &c);
  ct[idx] = c;
  st[idx] = si;
}

// ---------------------------------------------------------------------------
// int8 MFMA GEMM v3 (unchanged this round).
// ---------------------------------------------------------------------------
template <int OMODE>
__global__ __launch_bounds__(256) void gemm_i8(
    const int8_t* __restrict__ A8, const int8_t* __restrict__ W8,
    const float* __restrict__ wsc, const float* __restrict__ ctab,
    const float* __restrict__ stab, void* __restrict__ outp) {
  __shared__ __align__(16) int8_t Als[16384];  // 128 rows x 128 B
  __shared__ __align__(16) int8_t Bls[16384];
  const int t = threadIdx.x;
  const int w = t >> 6, lane = t & 63, g = lane >> 4, l15 = lane & 15;
  // 4x4 tile-group swizzle: 16 consecutive block IDs cover a 4x4 tile square
  const int G = blockIdx.x;
  const int within = G & 15, g16 = G >> 4;
  const int bn = ((g16 & 7) * 4 + (within & 3)) * 128;   // 32 n-tiles
  const int bm = ((g16 >> 3) * 4 + (within >> 2)) * 128; // 16 m-tiles

  // staging: wave w owns rows w*32 .. w*32+31 (4 DMA instrs x 8 rows each).
  const int srow = lane >> 3;                       // row within 8-row segment
  const int schunk = ((lane & 7) ^ srow) * 16;      // source chunk swizzle
  const int8_t* sA[4];
  const int8_t* sB[4];
  int8_t* dA[4];
  int8_t* dB[4];
#pragma unroll
  for (int i = 0; i < 4; ++i) {
    const int row = w * 32 + i * 8 + srow;
    sA[i] = A8 + (size_t)(bm + row) * D_DIM + schunk;
    sB[i] = W8 + (size_t)(bn + row) * D_DIM + schunk;
    dA[i] = Als + w * 4096 + i * 1024;
    dB[i] = Bls + w * 4096 + i * 1024;
  }

  v4i acc[8][2];
#pragma unroll
  for (int i = 0; i < 8; ++i) {
    acc[i][0] = (v4i){0, 0, 0, 0};
    acc[i][1] = (v4i){0, 0, 0, 0};
  }

  for (int k0 = 0; k0 < D_DIM; k0 += 128) {
#pragma unroll
    for (int i = 0; i < 4; ++i) {
      gl_lds16(sA[i] + k0, dA[i]);
      gl_lds16(sB[i] + k0, dB[i]);
    }
    __syncthreads();  // vmcnt drained before frag reads
#pragma unroll
    for (int kk = 0; kk < 2; ++kk) {
      const int coff = (((kk << 2) | g) ^ (l15 & 7)) * 16;
      const v4i bf0 = *(const v4i*)(Bls + (w * 16 + l15) * 128 + coff);
      const v4i bf1 = *(const v4i*)(Bls + (w * 16 + 64 + l15) * 128 + coff);
#pragma unroll
      for (int mi = 0; mi < 8; ++mi) {
        const v4i af = *(const v4i*)(Als + (mi * 16 + l15) * 128 + coff);
        acc[mi][0] = __builtin_amdgcn_mfma_i32_16x16x64_i8(af, bf0, acc[mi][0], 0, 0, 0);
        acc[mi][1] = __builtin_amdgcn_mfma_i32_16x16x64_i8(af, bf1, acc[mi][1], 0, 0, 0);
      }
    }
    __syncthreads();  // reads done before next DMA overwrites
  }

  if (OMODE == 0 || OMODE == 1) {
    const int jcol = w * 16 + l15;  // 0..63 (head spans the 128-col tile)
    const float sc0 = 0.1f * wsc[bn + jcol];
    const float sc1 = 0.1f * wsc[bn + jcol + 64];
    int8_t* dst = (int8_t*)outp;
#pragma unroll
    for (int mi = 0; mi < 8; ++mi) {
#pragma unroll
      for (int r = 0; r < 4; ++r) {
        const int s = bm + mi * 16 + g * 4 + r;
        const float c = ctab[s * 64 + jcol];
        const float si = stab[s * 64 + jcol];
        const float x1 = (float)acc[mi][0][r] * sc0;
        const float x2 = (float)acc[mi][1][r] * sc1;
        dst[(size_t)s * D_DIM + bn + jcol] = (int8_t)quant128(x1 * c - x2 * si);
        dst[(size_t)s * D_DIM + bn + jcol + 64] = (int8_t)quant128(x2 * c + x1 * si);
      }
    }
  } else if (OMODE == 2) {
    _Float16* dst = (_Float16*)outp;  // quantized V value (int <=128, exact in f16)
#pragma unroll
    for (int jt = 0; jt < 2; ++jt) {
      const int col = bn + w * 16 + jt * 64 + l15;
      const float scv = 0.1f * wsc[col];
#pragma unroll
      for (int mi = 0; mi < 8; ++mi) {
#pragma unroll
        for (int r = 0; r < 4; ++r) {
          const int s = bm + mi * 16 + g * 4 + r;
          dst[(size_t)col * S_LEN + s] = (_Float16)quant128((float)acc[mi][jt][r] * scv);
        }
      }
    }
  } else {
    float* dst = (float*)outp;
#pragma unroll
    for (int jt = 0; jt < 2; ++jt) {
      const int col = bn + w * 16 + jt * 64 + l15;
      const float scv = 0.1f * wsc[col];
#pragma unroll
      for (int mi = 0; mi < 8; ++mi) {
#pragma unroll
        for (int r = 0; r < 4; ++r) {
          const int s = bm + mi * 16 + g * 4 + r;
          dst[(size_t)s * D_DIM + col] = (float)acc[mi][jt][r] * scv;
        }
      }
    }
  }
}

// ---------------------------------------------------------------------------
// Flash attention v5 — latency-bound fix.
// Block (x,y): j = 31-x (longest-first), head h = y. Wave w owns q-tile
// qt = 4j+w (16 rows). All four waves share the SAME causal key range
// (T = j+1 tiles of 64 keys), so the block runs one shared double-buffered
// K/V LDS pipeline (global_load_lds, GEMM-style XOR chunk swizzle) with ONE
// barrier per tile and NO cross-wave merge.
// Swapped QK^T: mfma(K,Q) puts each q-row in one lane column -> softmax max
// is 2 shfl_xor (not 16), alpha is one exp. K rows are staged under the slot
// permutation c(s) = 32*s5+16*s3+8*s2+4*s4+(s&3) (row-granular, DMA-able;
// V natural), which makes the exp'd P land exactly in the PV A-frag layout:
// ph0 = p[0..1][0..3], ph1 = p[2..3][0..3] — all in-lane, zero LDS P traffic.
// Denominator rides the MFMA pipe via ones-column (same f16 P as numerator).
// ---------------------------------------------------------------------------
__global__ __launch_bounds__(256, 3) void attn_v5(
    const int8_t* __restrict__ q8, const int8_t* __restrict__ k8,
    const _Float16* __restrict__ vT, int8_t* __restrict__ o8) {
  __shared__ __align__(16) int8_t Kls[2][8192];   // 64 slots x 128 B (d)
  __shared__ __align__(16) int8_t Vls[2][16384];  // 128 d x 128 B (64 keys f16)
  const int j = 31 - blockIdx.x;
  const int h = blockIdx.y;
  const int t = threadIdx.x;
  const int w = t >> 6, lane = t & 63, g = lane >> 4, l15 = lane & 15;
  const int T = j + 1;                 // shared by all 4 waves
  const int q0 = (4 * j + w) * 16;     // wave-private q-tile
  const int q_lane = q0 + l15;         // this lane's q-row (score column)
  const float SSCALE = 8.838834764831845e-4f;  // 0.01 / sqrt(128)
  const v8h vones = {(_Float16)1, (_Float16)1, (_Float16)1, (_Float16)1,
                     (_Float16)1, (_Float16)1, (_Float16)1, (_Float16)1};

  // --- per-thread DMA descriptors (constant across tiles) ---
  int k_src[2], v_src[4], kv_dst[4];
#pragma unroll
  for (int i = 0; i < 2; ++i) {
    const int lin = i * 256 + t;
    const int s = lin >> 3;
    const int cs = (lin & 7) ^ (s & 7);  // XOR bank swizzle via source chunk
    // slot s holds global key c(s) (bit permutation; see header comment)
    const int key = ((s >> 5) & 1) * 32 + ((s >> 3) & 1) * 16 +
                    ((s >> 2) & 1) * 8 + ((s >> 4) & 1) * 4 + (s & 3);
    k_src[i] = key * D_DIM + cs * 16;  // byte offset within K tile rows
  }
#pragma unroll
  for (int i = 0; i < 4; ++i) {
    const int lin = i * 256 + t;
    const int d = lin >> 3;
    const int cs = (lin & 7) ^ (d & 7);
    v_src[i] = d * S_LEN + cs * 8;  // f16 units; V keys in natural order
    kv_dst[i] = lin * 16;
  }
  const int8_t* kbg = k8 + (size_t)h * HDIM;
  const _Float16* vbg = vT + (size_t)h * HDIM * S_LEN;

  auto stage = [&](int kt, int b) {
    const int8_t* ks = kbg + (size_t)kt * (64 * D_DIM);
    const _Float16* vs = vbg + kt * 64;
#pragma unroll
    for (int i = 0; i < 2; ++i) gl_lds16(ks + k_src[i], Kls[b] + kv_dst[i]);
#pragma unroll
    for (int i = 0; i < 4; ++i) gl_lds16(vs + v_src[i], Vls[b] + kv_dst[i]);
  };

  // Q fragments (B-operand of swapped QK): rows q0..q0+15
  const v4i qa0 = *(const v4i*)(q8 + (size_t)q_lane * D_DIM + h * HDIM + g * 16);
  const v4i qa1 = *(const v4i*)(q8 + (size_t)q_lane * D_DIM + h * HDIM + 64 + g * 16);

  v4f o[8];
#pragma unroll
  for (int n = 0; n < 8; ++n) o[n] = (v4f){0.f, 0.f, 0.f, 0.f};
  v4f lacc = (v4f){0.f, 0.f, 0.f, 0.f};  // denom per o-row (q = g*4+r)
  float m_i = -INFINITY;                 // running max for q = q_lane

  stage(0, 0);

  for (int kt = 0; kt < T; ++kt) {
    const int b = kt & 1;
    __syncthreads();  // buf[b] DMA complete (vmcnt drain) + prior reads done
    if (kt + 1 < T) stage(kt + 1, b ^ 1);

    // ---- scores: swapped int8 MFMA; slot s = nt*16 + g*4 + r, col = q ----
    const int ksw = (l15 & 7);
    float sc[4][4];
#pragma unroll
    for (int nt = 0; nt < 4; ++nt) {
      const int8_t* kr = Kls[b] + (nt * 16 + l15) * 128;
      const v4i kb0 = *(const v4i*)(kr + ((g ^ ksw) * 16));
      const v4i kb1 = *(const v4i*)(kr + (((4 + g) ^ ksw) * 16));
      v4i c = (v4i){0, 0, 0, 0};
      c = __builtin_amdgcn_mfma_i32_16x16x64_i8(kb0, qa0, c, 0, 0, 0);
      c = __builtin_amdgcn_mfma_i32_16x16x64_i8(kb1, qa1, c, 0, 0, 0);
#pragma unroll
      for (int r = 0; r < 4; ++r) {
        float s = (float)c[r] * SSCALE;
        if (kt == T - 1) {  // causal mask on actual key = c(slot)
          const int key = kt * 64 + ((nt >> 1) << 5) + ((g >> 1) << 4) +
                          ((g & 1) << 3) + ((nt & 1) << 2) + r;
          if (key > q_lane) s = -1.0e30f;
        }
        sc[nt][r] = s;
      }
    }
    // ---- online softmax: per-lane column max + 2 shfl_xor across g ----
    float mx = fmaxf(fmaxf(fmaxf(sc[0][0], sc[0][1]), fmaxf(sc[0][2], sc[0][3])),
                     fmaxf(fmaxf(sc[1][0], sc[1][1]), fmaxf(sc[1][2], sc[1][3])));
    mx = fmaxf(mx, fmaxf(fmaxf(fmaxf(sc[2][0], sc[2][1]), fmaxf(sc[2][2], sc[2][3])),
                         fmaxf(fmaxf(sc[3][0], sc[3][1]), fmaxf(sc[3][2], sc[3][3]))));
    mx = fmaxf(mx, __shfl_xor(mx, 16));
    mx = fmaxf(mx, __shfl_xor(mx, 32));
    const float mnew = fmaxf(m_i, mx);
    const float alpha = __expf(m_i - mnew);
    m_i = mnew;

    float p[4][4];
#pragma unroll
    for (int nt = 0; nt < 4; ++nt)
#pragma unroll
      for (int r = 0; r < 4; ++r) p[nt][r] = __expf(sc[nt][r] - m_i);

    // P -> f16 A-frags, purely in-lane (slot permutation absorbed in K rows)
    v8h ph0, ph1;
#pragma unroll
    for (int e = 0; e < 8; ++e) {
      ph0[e] = (_Float16)p[e >> 2][e & 3];
      ph1[e] = (_Float16)p[2 + (e >> 2)][e & 3];
    }
    // alpha for this lane's o-rows (q = g*4+r): fetch from lane l15 = g*4+r
    float a_r[4];
#pragma unroll
    for (int r = 0; r < 4; ++r)
      a_r[r] = __shfl(alpha, (lane & 48) | (g * 4 + r));
#pragma unroll
    for (int n = 0; n < 8; ++n)
#pragma unroll
      for (int r = 0; r < 4; ++r) o[n][r] *= a_r[r];
#pragma unroll
    for (int r = 0; r < 4; ++r) lacc[r] *= a_r[r];

    __builtin_amdgcn_s_setprio(1);
    // denominator rides the MFMA pipe (B = ones); same f16 P as numerator
    lacc = __builtin_amdgcn_mfma_f32_16x16x32_f16(ph0, vones, lacc, 0, 0, 0);
    lacc = __builtin_amdgcn_mfma_f32_16x16x32_f16(ph1, vones, lacc, 0, 0, 0);
    // ---- PV: V from LDS (natural key order), XOR-swizzled b128 reads ----
#pragma unroll
    for (int nt = 0; nt < 8; ++nt) {
      const int8_t* vr = Vls[b] + (nt * 16 + l15) * 128;
      const v8h v0 = *(const v8h*)(vr + ((g ^ ksw) * 16));
      const v8h v1 = *(const v8h*)(vr + (((4 + g) ^ ksw) * 16));
      o[nt] = __builtin_amdgcn_mfma_f32_16x16x32_f16(ph0, v0, o[nt], 0, 0, 0);
      o[nt] = __builtin_amdgcn_mfma_f32_16x16x32_f16(ph1, v1, o[nt], 0, 0, 0);
    }
    __builtin_amdgcn_s_setprio(0);
  }

  // ---- epilogue: normalize + int8 quantize, wave-private, no barrier ----
#pragma unroll
  for (int r = 0; r < 4; ++r) {
    const float rL = 1.0f / lacc[r];
    const size_t row = (size_t)(q0 + g * 4 + r) * D_DIM + h * HDIM;
#pragma unroll
    for (int nt = 0; nt < 8; ++nt) {
      // out = res*0.1/L; out_q = rint(out/0.1) clamp +-127 (0.1 cancels)
      const int q = (int)fminf(fmaxf(rintf(o[nt][r] * rL), -127.f), 127.f);
      o8[row + nt * 16 + l15] = (int8_t)q;
    }
  }
}

// ---------------------------------------------------------------------------
extern "C" void kernel_launch(void* const* d_in, const int* in_sizes, int n_in,
                              void* d_out, int out_size, void* d_ws, size_t ws_size,
                              hipStream_t stream) {
  (void)in_sizes; (void)n_in; (void)out_size; (void)ws_size;
  const float* hidden = (const float*)d_in[0];
  const float* wq = (const float*)d_in[1];
  const float* wk = (const float*)d_in[2];
  const float* wv = (const float*)d_in[3];
  const float* wo = (const float*)d_in[4];
  const float* sq = (const float*)d_in[5];
  const float* sk = (const float*)d_in[6];
  const float* sv = (const float*)d_in[7];
  const float* so = (const float*)d_in[8];
  // d_in[9] = attention_mask (pure causal; handled analytically)
  const int* pos = (const int*)d_in[10];
  float* out = (float*)d_out;

  char* ws = (char*)d_ws;
  int8_t* h8 = (int8_t*)ws;                                   // 8 MB (later o8)
  int8_t* q8 = (int8_t*)(ws + (8ull << 20));                  // 8 MB
  int8_t* k8 = (int8_t*)(ws + (16ull << 20));                 // 8 MB
  _Float16* vT = (_Float16*)(ws + (24ull << 20));             // 16 MB f16 [D][S]
  int8_t* w8a = (int8_t*)(ws + (40ull << 20));                // 16 MB (wq, later wo)
  int8_t* w8b = (int8_t*)(ws + (56ull << 20));                // 16 MB (wk)
  int8_t* w8c = (int8_t*)(ws + (72ull << 20));                // 16 MB (wv)
  float* ctab = (float*)(ws + (88ull << 20));                 // 512 KB
  float* stab = (float*)(ws + (88ull << 20) + (512ull << 10));
  int8_t* o8 = h8;  // h8 dead after v-GEMM; attn writes o8 there

  hipLaunchKernelGGL(rope_tab_k, dim3(512), dim3(256), 0, stream, pos, ctab, stab);
  hipLaunchKernelGGL(quant_hidden_k, dim3(8192), dim3(256), 0, stream, hidden, h8);
  hipLaunchKernelGGL(wconv3_k, dim3(49152), dim3(256), 0, stream, wq, wk, wv, w8a);

  const dim3 gg(512), gb(256);
  hipLaunchKernelGGL((gemm_i8<0>), gg, gb, 0, stream, h8, w8a, sq, ctab, stab, (void*)q8);
  hipLaunchKernelGGL((gemm_i8<1>), gg, gb, 0, stream, h8, w8b, sk, ctab, stab, (void*)k8);
  hipLaunchKernelGGL((gemm_i8<2>), gg, gb, 0, stream, h8, w8c, sv, ctab, stab, (void*)vT);
  hipLaunchKernelGGL(wconv_k, dim3(16384), dim3(256), 0, stream, wo, w8a);  // wq dead
  hipLaunchKernelGGL(attn_v5, dim3(32, 32), dim3(256), 0, stream, q8, k8, vT, o8);
  hipLaunchKernelGGL((gemm_i8<3>), gg, gb, 0, stream, o8, w8a, so, ctab, stab, (void*)out);
}

// Round 2
// 518.853 us; speedup vs baseline: 1.2831x; 1.1088x over previous
//
#include <hip/hip_runtime.h>
#include <math.h>
#include <stdint.h>

#define S_LEN 2048
#define D_DIM 4096
#define NHEAD 32
#define HDIM  128

typedef int      v4i __attribute__((ext_vector_type(4)));
typedef float    v4f __attribute__((ext_vector_type(4)));
typedef _Float16 v8h __attribute__((ext_vector_type(8)));

__device__ __forceinline__ float quant128(float x) {
  return fminf(fmaxf(rintf(x / 0.1f), -128.f), 127.f);
}
// async 16B global->LDS DMA; LDS side is wave-uniform base + lane*16
__device__ __forceinline__ void gl_lds16(const void* g, void* l) {
  __builtin_amdgcn_global_load_lds(
      (const __attribute__((address_space(1))) void*)g,
      (__attribute__((address_space(3))) void*)l, 16, 0, 0);
}

// ---------------- prep kernels ----------------
__global__ __launch_bounds__(256) void quant_hidden_k(const float* __restrict__ in,
                                                      int8_t* __restrict__ out) {
  const int idx = blockIdx.x * 256 + threadIdx.x;
  const float4 v = ((const float4*)in)[idx];
  const int q0 = (int)quant128(v.x), q1 = (int)quant128(v.y);
  const int q2 = (int)quant128(v.z), q3 = (int)quant128(v.w);
  ((int*)out)[idx] = (q0 & 0xff) | ((q1 & 0xff) << 8) | ((q2 & 0xff) << 16) | ((q3 & 0xff) << 24);
}

// fused f32->int8 convert of wq,wk,wv into one contiguous 48MB dst
__global__ __launch_bounds__(256) void wconv3_k(const float* __restrict__ a,
                                                const float* __restrict__ b,
                                                const float* __restrict__ c,
                                                int8_t* __restrict__ out) {
  const int which = blockIdx.x >> 14;
  const int sub = blockIdx.x & 16383;
  const float* src = (which == 0) ? a : (which == 1) ? b : c;
  const int idx = sub * 256 + threadIdx.x;
  const float4 v = ((const float4*)src)[idx];  // int4-valued floats, exact
  const int q0 = __float2int_rn(v.x), q1 = __float2int_rn(v.y);
  const int q2 = __float2int_rn(v.z), q3 = __float2int_rn(v.w);
  ((int*)out)[(size_t)which * 4194304 + idx] =
      (q0 & 0xff) | ((q1 & 0xff) << 8) | ((q2 & 0xff) << 16) | ((q3 & 0xff) << 24);
}

__global__ __launch_bounds__(256) void wconv_k(const float* __restrict__ in,
                                               int8_t* __restrict__ out) {
  const int idx = blockIdx.x * 256 + threadIdx.x;
  const float4 v = ((const float4*)in)[idx];
  const int q0 = __float2int_rn(v.x), q1 = __float2int_rn(v.y);
  const int q2 = __float2int_rn(v.z), q3 = __float2int_rn(v.w);
  ((int*)out)[idx] = (q0 & 0xff) | ((q1 & 0xff) << 8) | ((q2 & 0xff) << 16) | ((q3 & 0xff) << 24);
}

__global__ __launch_bounds__(256) void rope_tab_k(const int* __restrict__ pos,
                                                  float* __restrict__ ct,
                                                  float* __restrict__ st) {
  const int idx = blockIdx.x * 256 + threadIdx.x;  // [S][64]
  const int s = idx >> 6, j = idx & 63;
  const float inv = exp2f((float)j * -0.20762050593046016f);  // 10000^(-j/64)
  const float a = (float)pos[s] * inv;
  float si, c;
  sincosf(a, &si, &c);
  ct[idx] = c;
  st[idx] = si;
}

// ---------------------------------------------------------------------------
// int8 MFMA GEMM v4 — T3+T4 counted-vmcnt pipeline (8-phase-lite).
// Tile 128(m) x 256(n), BK=128, 8 waves (2m x 4n, per-wave 64x64 = acc[4][4]).
// Triple-buffered LDS (3 x 48KB = 144KB), 2-deep prefetch via global_load_lds:
// per K-tile exactly ONE raw s_barrier + ONE counted s_waitcnt vmcnt(6)
// (never a full drain in the loop). stage(t+2) issued right after the
// barrier; buffer t%3 compile-time via 3x loop unroll. XOR chunk swizzle on
// stage/read identical to the proven v3 scheme (0 bank conflicts measured).
// MODE 0: fused QKV (N=12288, weights contiguous), per-segment epilogue:
//   seg 0/1 -> RoPE + int8 quant into q8/k8 (head-half pairs kept wave-local
//   by the n-column mapping), seg 2 -> f16 transpose store into vT.
// MODE 1: out-projection, f32 output.
// ---------------------------------------------------------------------------
template <int MODE>
__global__ __launch_bounds__(512, 1) void gemm8p(
    const int8_t* __restrict__ A8, const int8_t* __restrict__ W8,
    const float* __restrict__ s0, const float* __restrict__ s1,
    const float* __restrict__ s2, const float* __restrict__ ctab,
    const float* __restrict__ stab, void* __restrict__ out0,
    void* __restrict__ out1, void* __restrict__ out2) {
  __shared__ __align__(16) int8_t LS[3 * 16384 + 3 * 32768];  // 144 KB
  int8_t* const Abase = LS;            // 3 x 16KB (128 rows x 128B)
  int8_t* const Bbase = LS + 49152;    // 3 x 32KB (256 rows x 128B)

  const int t = threadIdx.x;
  const int w = t >> 6, lane = t & 63, g = lane >> 4, l15 = lane & 15;
  const int wm = w >> 2, wn = w & 3;  // 2 x 4 wave grid

  // block tile: 4x4 tile-group swizzle for L2 locality
  const int G = blockIdx.x;
  const int within = G & 15, g16 = G >> 4;
  const int bm = ((g16 & 3) * 4 + (within >> 2)) * 128;
  const int bn = ((g16 >> 2) * 4 + (within & 3)) * 256;

  // ---- staging descriptors: lane -> (row_off = lane>>3, chunk = lane&7),
  // source chunk XOR-swizzled so LDS slot c of row r holds chunk c^(r&7).
  const int rowo = lane >> 3;
  const int schunk = ((lane & 7) ^ rowo) * 16;
  const int8_t* srcA[2];
  const int8_t* srcB[4];
#pragma unroll
  for (int i = 0; i < 2; ++i)
    srcA[i] = A8 + (size_t)(bm + w * 16 + i * 8 + rowo) * D_DIM + schunk;
#pragma unroll
  for (int i = 0; i < 4; ++i)
    srcB[i] = W8 + (size_t)(bn + w * 32 + i * 8 + rowo) * D_DIM + schunk;

#define STAGE(KT, BI)                                                       \
  {                                                                         \
    const int kof_ = (KT) * 128;                                            \
    int8_t* Ad_ = Abase + (BI) * 16384 + w * 2048;                          \
    int8_t* Bd_ = Bbase + (BI) * 32768 + w * 4096;                          \
    _Pragma("unroll") for (int i_ = 0; i_ < 2; ++i_)                        \
        gl_lds16(srcA[i_] + kof_, Ad_ + i_ * 1024);                         \
    _Pragma("unroll") for (int i_ = 0; i_ < 4; ++i_)                        \
        gl_lds16(srcB[i_] + kof_, Bd_ + i_ * 1024);                         \
  }

  // per-wave n-column base; ncol(ni) = nc0 + (ni&1)*16 + (ni>>1)*64.
  // (wn>>1) picks the 128-head, (wn&1) the 32-sub — so frag ni and ni+2 are
  // the (d, d+64) RoPE pair of the SAME head, wave-locally.
  const int nc0 = (wn & 1) * 32 + (wn >> 1) * 128;

  v4i acc[4][4];
#pragma unroll
  for (int mi = 0; mi < 4; ++mi)
#pragma unroll
    for (int ni = 0; ni < 4; ++ni) acc[mi][ni] = (v4i){0, 0, 0, 0};

  STAGE(0, 0)
  STAGE(1, 1)

  for (int t3 = 0; t3 < 33; t3 += 3) {
#pragma unroll
    for (int u = 0; u < 3; ++u) {
      const int kt = t3 + u;
      if (kt < 32) {
        if (kt + 1 < 32)
          asm volatile("s_waitcnt vmcnt(6)" ::: "memory");  // own stage(kt) done
        else
          asm volatile("s_waitcnt vmcnt(0)" ::: "memory");  // tail
        __builtin_amdgcn_s_barrier();
        if (kt + 2 < 32) STAGE(kt + 2, ((u + 2) % 3))
        const int8_t* Ab = Abase + u * 16384;
        const int8_t* Bb = Bbase + u * 32768;
#pragma unroll
        for (int kk = 0; kk < 2; ++kk) {
          const int coff = (((kk << 2) | g) ^ (l15 & 7)) * 16;
          v4i bf[4], af[4];
#pragma unroll
          for (int ni = 0; ni < 4; ++ni) {
            const int nrow = nc0 + (ni & 1) * 16 + (ni >> 1) * 64 + l15;
            bf[ni] = *(const v4i*)(Bb + nrow * 128 + coff);
          }
#pragma unroll
          for (int mi = 0; mi < 4; ++mi)
            af[mi] = *(const v4i*)(Ab + (wm * 64 + mi * 16 + l15) * 128 + coff);
          __builtin_amdgcn_s_setprio(1);
#pragma unroll
          for (int mi = 0; mi < 4; ++mi)
#pragma unroll
            for (int ni = 0; ni < 4; ++ni)
              acc[mi][ni] =
                  __builtin_amdgcn_mfma_i32_16x16x64_i8(af[mi], bf[ni], acc[mi][ni], 0, 0, 0);
          __builtin_amdgcn_s_setprio(0);
        }
      }
    }
  }
#undef STAGE

  // ---- epilogue (C/D map: row = g*4+r, col = l15 within each 16x16) ----
  const int srow0 = bm + wm * 64;
  if (MODE == 1) {
    float* dst = (float*)out0;
#pragma unroll
    for (int ni = 0; ni < 4; ++ni) {
      const int col = bn + nc0 + (ni & 1) * 16 + (ni >> 1) * 64 + l15;
      const float sc = 0.1f * s0[col];
#pragma unroll
      for (int mi = 0; mi < 4; ++mi)
#pragma unroll
        for (int r = 0; r < 4; ++r)
          dst[(size_t)(srow0 + mi * 16 + g * 4 + r) * D_DIM + col] =
              (float)acc[mi][ni][r] * sc;
    }
  } else {
    const int seg = bn >> 12;        // 0=Q 1=K 2=V (BN=256 < 4096, uniform)
    const int bcol = bn & 4095;
    if (seg == 2) {
      _Float16* dst = (_Float16*)out2;
#pragma unroll
      for (int ni = 0; ni < 4; ++ni) {
        const int col = bcol + nc0 + (ni & 1) * 16 + (ni >> 1) * 64 + l15;
        const float scv = 0.1f * s2[col];
#pragma unroll
        for (int mi = 0; mi < 4; ++mi)
#pragma unroll
          for (int r = 0; r < 4; ++r) {
            const int s = srow0 + mi * 16 + g * 4 + r;
            dst[(size_t)col * S_LEN + s] = (_Float16)quant128((float)acc[mi][ni][r] * scv);
          }
      }
    } else {
      const float* wsc = seg ? s1 : s0;
      int8_t* dst = seg ? (int8_t*)out1 : (int8_t*)out0;
      const int hb = bcol + (wn >> 1) * 128;  // head base column
#pragma unroll
      for (int ni = 0; ni < 2; ++ni) {        // low-d frag; pair is ni+2
        const int dlo = (wn & 1) * 32 + ni * 16 + l15;  // 0..63 within head
        const int clo = hb + dlo;
        const float sc0 = 0.1f * wsc[clo];
        const float sc1 = 0.1f * wsc[clo + 64];
#pragma unroll
        for (int mi = 0; mi < 4; ++mi)
#pragma unroll
          for (int r = 0; r < 4; ++r) {
            const int s = srow0 + mi * 16 + g * 4 + r;
            const float c = ctab[s * 64 + dlo];
            const float si = stab[s * 64 + dlo];
            const float x1 = (float)acc[mi][ni][r] * sc0;
            const float x2 = (float)acc[mi][ni + 2][r] * sc1;
            dst[(size_t)s * D_DIM + clo] = (int8_t)quant128(x1 * c - x2 * si);
            dst[(size_t)s * D_DIM + clo + 64] = (int8_t)quant128(x2 * c + x1 * si);
          }
      }
    }
  }
}

// ---------------------------------------------------------------------------
// Flash attention v5 (unchanged this round).
// ---------------------------------------------------------------------------
__global__ __launch_bounds__(256, 3) void attn_v5(
    const int8_t* __restrict__ q8, const int8_t* __restrict__ k8,
    const _Float16* __restrict__ vT, int8_t* __restrict__ o8) {
  __shared__ __align__(16) int8_t Kls[2][8192];   // 64 slots x 128 B (d)
  __shared__ __align__(16) int8_t Vls[2][16384];  // 128 d x 128 B (64 keys f16)
  const int j = 31 - blockIdx.x;
  const int h = blockIdx.y;
  const int t = threadIdx.x;
  const int w = t >> 6, lane = t & 63, g = lane >> 4, l15 = lane & 15;
  const int T = j + 1;                 // shared by all 4 waves
  const int q0 = (4 * j + w) * 16;     // wave-private q-tile
  const int q_lane = q0 + l15;         // this lane's q-row (score column)
  const float SSCALE = 8.838834764831845e-4f;  // 0.01 / sqrt(128)
  const v8h vones = {(_Float16)1, (_Float16)1, (_Float16)1, (_Float16)1,
                     (_Float16)1, (_Float16)1, (_Float16)1, (_Float16)1};

  // --- per-thread DMA descriptors (constant across tiles) ---
  int k_src[2], v_src[4], kv_dst[4];
#pragma unroll
  for (int i = 0; i < 2; ++i) {
    const int lin = i * 256 + t;
    const int s = lin >> 3;
    const int cs = (lin & 7) ^ (s & 7);  // XOR bank swizzle via source chunk
    // slot s holds global key c(s) (bit permutation; see header comment)
    const int key = ((s >> 5) & 1) * 32 + ((s >> 3) & 1) * 16 +
                    ((s >> 2) & 1) * 8 + ((s >> 4) & 1) * 4 + (s & 3);
    k_src[i] = key * D_DIM + cs * 16;  // byte offset within K tile rows
  }
#pragma unroll
  for (int i = 0; i < 4; ++i) {
    const int lin = i * 256 + t;
    const int d = lin >> 3;
    const int cs = (lin & 7) ^ (d & 7);
    v_src[i] = d * S_LEN + cs * 8;  // f16 units; V keys in natural order
    kv_dst[i] = lin * 16;
  }
  const int8_t* kbg = k8 + (size_t)h * HDIM;
  const _Float16* vbg = vT + (size_t)h * HDIM * S_LEN;

  auto stage = [&](int kt, int b) {
    const int8_t* ks = kbg + (size_t)kt * (64 * D_DIM);
    const _Float16* vs = vbg + kt * 64;
#pragma unroll
    for (int i = 0; i < 2; ++i) gl_lds16(ks + k_src[i], Kls[b] + kv_dst[i]);
#pragma unroll
    for (int i = 0; i < 4; ++i) gl_lds16(vs + v_src[i], Vls[b] + kv_dst[i]);
  };

  // Q fragments (B-operand of swapped QK): rows q0..q0+15
  const v4i qa0 = *(const v4i*)(q8 + (size_t)q_lane * D_DIM + h * HDIM + g * 16);
  const v4i qa1 = *(const v4i*)(q8 + (size_t)q_lane * D_DIM + h * HDIM + 64 + g * 16);

  v4f o[8];
#pragma unroll
  for (int n = 0; n < 8; ++n) o[n] = (v4f){0.f, 0.f, 0.f, 0.f};
  v4f lacc = (v4f){0.f, 0.f, 0.f, 0.f};  // denom per o-row (q = g*4+r)
  float m_i = -INFINITY;                 // running max for q = q_lane

  stage(0, 0);

  for (int kt = 0; kt < T; ++kt) {
    const int b = kt & 1;
    __syncthreads();  // buf[b] DMA complete (vmcnt drain) + prior reads done
    if (kt + 1 < T) stage(kt + 1, b ^ 1);

    // ---- scores: swapped int8 MFMA; slot s = nt*16 + g*4 + r, col = q ----
    const int ksw = (l15 & 7);
    float sc[4][4];
#pragma unroll
    for (int nt = 0; nt < 4; ++nt) {
      const int8_t* kr = Kls[b] + (nt * 16 + l15) * 128;
      const v4i kb0 = *(const v4i*)(kr + ((g ^ ksw) * 16));
      const v4i kb1 = *(const v4i*)(kr + (((4 + g) ^ ksw) * 16));
      v4i c = (v4i){0, 0, 0, 0};
      c = __builtin_amdgcn_mfma_i32_16x16x64_i8(kb0, qa0, c, 0, 0, 0);
      c = __builtin_amdgcn_mfma_i32_16x16x64_i8(kb1, qa1, c, 0, 0, 0);
#pragma unroll
      for (int r = 0; r < 4; ++r) {
        float s = (float)c[r] * SSCALE;
        if (kt == T - 1) {  // causal mask on actual key = c(slot)
          const int key = kt * 64 + ((nt >> 1) << 5) + ((g >> 1) << 4) +
                          ((g & 1) << 3) + ((nt & 1) << 2) + r;
          if (key > q_lane) s = -1.0e30f;
        }
        sc[nt][r] = s;
      }
    }
    // ---- online softmax: per-lane column max + 2 shfl_xor across g ----
    float mx = fmaxf(fmaxf(fmaxf(sc[0][0], sc[0][1]), fmaxf(sc[0][2], sc[0][3])),
                     fmaxf(fmaxf(sc[1][0], sc[1][1]), fmaxf(sc[1][2], sc[1][3])));
    mx = fmaxf(mx, fmaxf(fmaxf(fmaxf(sc[2][0], sc[2][1]), fmaxf(sc[2][2], sc[2][3])),
                         fmaxf(fmaxf(sc[3][0], sc[3][1]), fmaxf(sc[3][2], sc[3][3]))));
    mx = fmaxf(mx, __shfl_xor(mx, 16));
    mx = fmaxf(mx, __shfl_xor(mx, 32));
    const float mnew = fmaxf(m_i, mx);
    const float alpha = __expf(m_i - mnew);
    m_i = mnew;

    float p[4][4];
#pragma unroll
    for (int nt = 0; nt < 4; ++nt)
#pragma unroll
      for (int r = 0; r < 4; ++r) p[nt][r] = __expf(sc[nt][r] - m_i);

    // P -> f16 A-frags, purely in-lane (slot permutation absorbed in K rows)
    v8h ph0, ph1;
#pragma unroll
    for (int e = 0; e < 8; ++e) {
      ph0[e] = (_Float16)p[e >> 2][e & 3];
      ph1[e] = (_Float16)p[2 + (e >> 2)][e & 3];
    }
    // alpha for this lane's o-rows (q = g*4+r): fetch from lane l15 = g*4+r
    float a_r[4];
#pragma unroll
    for (int r = 0; r < 4; ++r)
      a_r[r] = __shfl(alpha, (lane & 48) | (g * 4 + r));
#pragma unroll
    for (int n = 0; n < 8; ++n)
#pragma unroll
      for (int r = 0; r < 4; ++r) o[n][r] *= a_r[r];
#pragma unroll
    for (int r = 0; r < 4; ++r) lacc[r] *= a_r[r];

    __builtin_amdgcn_s_setprio(1);
    // denominator rides the MFMA pipe (B = ones); same f16 P as numerator
    lacc = __builtin_amdgcn_mfma_f32_16x16x32_f16(ph0, vones, lacc, 0, 0, 0);
    lacc = __builtin_amdgcn_mfma_f32_16x16x32_f16(ph1, vones, lacc, 0, 0, 0);
    // ---- PV: V from LDS (natural key order), XOR-swizzled b128 reads ----
#pragma unroll
    for (int nt = 0; nt < 8; ++nt) {
      const int8_t* vr = Vls[b] + (nt * 16 + l15) * 128;
      const v8h v0 = *(const v8h*)(vr + ((g ^ ksw) * 16));
      const v8h v1 = *(const v8h*)(vr + (((4 + g) ^ ksw) * 16));
      o[nt] = __builtin_amdgcn_mfma_f32_16x16x32_f16(ph0, v0, o[nt], 0, 0, 0);
      o[nt] = __builtin_amdgcn_mfma_f32_16x16x32_f16(ph1, v1, o[nt], 0, 0, 0);
    }
    __builtin_amdgcn_s_setprio(0);
  }

  // ---- epilogue: normalize + int8 quantize, wave-private, no barrier ----
#pragma unroll
  for (int r = 0; r < 4; ++r) {
    const float rL = 1.0f / lacc[r];
    const size_t row = (size_t)(q0 + g * 4 + r) * D_DIM + h * HDIM;
#pragma unroll
    for (int nt = 0; nt < 8; ++nt) {
      // out = res*0.1/L; out_q = rint(out/0.1) clamp +-127 (0.1 cancels)
      const int q = (int)fminf(fmaxf(rintf(o[nt][r] * rL), -127.f), 127.f);
      o8[row + nt * 16 + l15] = (int8_t)q;
    }
  }
}

// ---------------------------------------------------------------------------
extern "C" void kernel_launch(void* const* d_in, const int* in_sizes, int n_in,
                              void* d_out, int out_size, void* d_ws, size_t ws_size,
                              hipStream_t stream) {
  (void)in_sizes; (void)n_in; (void)out_size; (void)ws_size;
  const float* hidden = (const float*)d_in[0];
  const float* wq = (const float*)d_in[1];
  const float* wk = (const float*)d_in[2];
  const float* wv = (const float*)d_in[3];
  const float* wo = (const float*)d_in[4];
  const float* sq = (const float*)d_in[5];
  const float* sk = (const float*)d_in[6];
  const float* sv = (const float*)d_in[7];
  const float* so = (const float*)d_in[8];
  // d_in[9] = attention_mask (pure causal; handled analytically)
  const int* pos = (const int*)d_in[10];
  float* out = (float*)d_out;

  char* ws = (char*)d_ws;
  int8_t* h8 = (int8_t*)ws;                                   // 8 MB (later o8)
  int8_t* q8 = (int8_t*)(ws + (8ull << 20));                  // 8 MB
  int8_t* k8 = (int8_t*)(ws + (16ull << 20));                 // 8 MB
  _Float16* vT = (_Float16*)(ws + (24ull << 20));             // 16 MB f16 [D][S]
  int8_t* w8a = (int8_t*)(ws + (40ull << 20));                // 16 MB (wq, later wo)
  int8_t* w8b = (int8_t*)(ws + (56ull << 20));                // 16 MB (wk)
  int8_t* w8c = (int8_t*)(ws + (72ull << 20));                // 16 MB (wv)
  float* ctab = (float*)(ws + (88ull << 20));                 // 512 KB
  float* stab = (float*)(ws + (88ull << 20) + (512ull << 10));
  int8_t* o8 = h8;  // h8 dead after v-GEMM; attn writes o8 there

  hipLaunchKernelGGL(rope_tab_k, dim3(512), dim3(256), 0, stream, pos, ctab, stab);
  hipLaunchKernelGGL(quant_hidden_k, dim3(8192), dim3(256), 0, stream, hidden, h8);
  hipLaunchKernelGGL(wconv3_k, dim3(49152), dim3(256), 0, stream, wq, wk, wv, w8a);

  // fused QKV: 16 m-tiles x 48 n-tiles = 768 blocks (3 clean rounds @ 1/CU)
  hipLaunchKernelGGL((gemm8p<0>), dim3(768), dim3(512), 0, stream, h8, w8a,
                     sq, sk, sv, ctab, stab, (void*)q8, (void*)k8, (void*)vT);
  hipLaunchKernelGGL(wconv_k, dim3(16384), dim3(256), 0, stream, wo, w8a);  // QKV weights dead
  hipLaunchKernelGGL(attn_v5, dim3(32, 32), dim3(256), 0, stream, q8, k8, vT, o8);
  // out-proj: 16 x 16 = 256 blocks (exactly 1/CU)
  hipLaunchKernelGGL((gemm8p<1>), dim3(256), dim3(512), 0, stream, o8, w8a,
                     so, so, so, ctab, stab, (void*)out, (void*)out, (void*)out);
}